// Round 4
// baseline (484.856 us; speedup 1.0000x reference)
//
#include <hip/hip_runtime.h>

#define H 8
#define C 64
#define HC 512
#define NEG 0.2f

typedef __attribute__((ext_vector_type(8))) short bf16x8;
typedef __attribute__((ext_vector_type(4))) float f32x4;
typedef __attribute__((ext_vector_type(4))) short short4v;

__device__ __forceinline__ float leaky(float x) { return x > 0.f ? x : NEG * x; }

__device__ __forceinline__ short f2bf(float x) {
    unsigned u = __float_as_uint(x);
    unsigned r = (u + 0x7fffu + ((u >> 16) & 1u)) >> 16;
    return (short)r;
}
__device__ __forceinline__ float bf2f(short s) {
    return __uint_as_float(((unsigned)(unsigned short)s) << 16);
}

#define GLOAD_LDS16(gp, lp) \
  __builtin_amdgcn_global_load_lds((const __attribute__((address_space(1))) unsigned int*)(gp), \
                                   (__attribute__((address_space(3))) unsigned int*)(lp), 16, 0, 0)

// ---------------- CSR build (dst-sorted) ----------------
__global__ void k_degree(const int* __restrict__ ei, int E, int N, int* __restrict__ deg) {
    int e = blockIdx.x * blockDim.x + threadIdx.x;
    int Et = E + N;
    if (e >= Et) return;
    int d = (e < E) ? ei[E + e] : (e - E);
    atomicAdd(&deg[d], 1);
}

__global__ __launch_bounds__(1024) void k_scan(const int* __restrict__ deg, int N, int* __restrict__ row_start) {
    __shared__ int part[1024];
    int t = threadIdx.x;
    int chunk = (N + 1023) >> 10;
    int lo = t * chunk, hi = min(lo + chunk, N);
    int s = 0;
    for (int i = lo; i < hi; ++i) s += deg[i];
    part[t] = s;
    __syncthreads();
    for (int off = 1; off < 1024; off <<= 1) {
        int v = (t >= off) ? part[t - off] : 0;
        __syncthreads();
        part[t] += v;
        __syncthreads();
    }
    int base = (t == 0) ? 0 : part[t - 1];
    for (int i = lo; i < hi; ++i) { row_start[i] = base; base += deg[i]; }
    if (t == 1023) row_start[N] = part[1023];
}

__global__ void k_fill(const int* __restrict__ ei, int E, int N,
                       const int* __restrict__ row_start, int* __restrict__ cursor,
                       int* __restrict__ csr_src) {
    int e = blockIdx.x * blockDim.x + threadIdx.x;
    int Et = E + N;
    if (e >= Et) return;
    int d, s;
    if (e < E) { s = ei[e]; d = ei[E + e]; } else { s = e - E; d = s; }
    int pos = atomicAdd(&cursor[d], 1);
    csr_src[row_start[d] + pos] = s;
}

// ---------------- split fp32 -> bf16 hi + bf16 lo ----------------
__global__ void k_split4(const float* __restrict__ in, short* __restrict__ hi,
                         short* __restrict__ lo, int n4) {
    int i = blockIdx.x * blockDim.x + threadIdx.x;
    if (i >= n4) return;
    float4 v = reinterpret_cast<const float4*>(in)[i];
    short4v h, l;
    float vv[4] = {v.x, v.y, v.z, v.w};
    #pragma unroll
    for (int j = 0; j < 4; ++j) {
        short hh = f2bf(vv[j]);
        h[j] = hh;
        l[j] = f2bf(vv[j] - bf2f(hh));
    }
    reinterpret_cast<short4v*>(hi)[i] = h;
    reinterpret_cast<short4v*>(lo)[i] = l;
}

// W [K][Nc] fp32 -> Wt hi/lo [Nc][K] bf16
__global__ void k_tsplit(const float* __restrict__ W, short* __restrict__ th,
                         short* __restrict__ tl, int K, int Nc) {
    int idx = blockIdx.x * blockDim.x + threadIdx.x;
    if (idx >= K * Nc) return;
    int c = idx / K, k = idx - c * K;
    float v = W[(long)k * Nc + c];
    short hh = f2bf(v);
    th[idx] = hh;
    tl[idx] = f2bf(v - bf2f(hh));
}

// ---------------- MFMA GEMM + fused attention-dot epilogue ----------------
// C written HEAD-MAJOR: hpre[head][Mpad][64]. 3-pass split bf16 MFMA.
// Tile 128x128, BK=32, 4 waves. Also emits e_src/e_dst per (row, head).
__global__ __launch_bounds__(256) void k_gemm_mfma(const short* __restrict__ Ah, const short* __restrict__ Al,
                                                   const short* __restrict__ Bh, const short* __restrict__ Bl,
                                                   float* __restrict__ Cc, int M, int K, int Mpad,
                                                   const float* __restrict__ a_src, const float* __restrict__ a_dst,
                                                   float* __restrict__ e_src, float* __restrict__ e_dst) {
    __shared__ short lAh[4096], lAl[4096], lBh[4096], lBl[4096];
    int tid = threadIdx.x;
    int w = tid >> 6, lane = tid & 63;
    int wr = w >> 1, wc = w & 1;
    int r0 = blockIdx.x * 128, c0 = blockIdx.y * 128;
    f32x4 acc[4][4] = {};
    int frag_off = ((lane >> 4) * 16 + (lane & 15)) * 8;

    for (int k0 = 0; k0 < K; k0 += 32) {
        __syncthreads();
        #pragma unroll
        for (int it = 0; it < 2; ++it) {
            int slot = it * 256 + tid;
            int rb = slot >> 6, kc = (slot >> 4) & 3, r16 = slot & 15;
            long ga = (long)(r0 + rb * 16 + r16) * K + k0 + kc * 8;
            long gb = (long)(c0 + rb * 16 + r16) * K + k0 + kc * 8;
            int ldst = (it * 256 + w * 64) * 8;
            GLOAD_LDS16(Ah + ga, lAh + ldst);
            GLOAD_LDS16(Al + ga, lAl + ldst);
            GLOAD_LDS16(Bh + gb, lBh + ldst);
            GLOAD_LDS16(Bl + gb, lBl + ldst);
        }
        __syncthreads();
        bf16x8 fah[4], fal[4], fbh[4], fbl[4];
        #pragma unroll
        for (int m = 0; m < 4; ++m) {
            int sa = (wr * 4 + m) * 512 + frag_off;
            fah[m] = *reinterpret_cast<bf16x8*>(&lAh[sa]);
            fal[m] = *reinterpret_cast<bf16x8*>(&lAl[sa]);
            int sb = (wc * 4 + m) * 512 + frag_off;
            fbh[m] = *reinterpret_cast<bf16x8*>(&lBh[sb]);
            fbl[m] = *reinterpret_cast<bf16x8*>(&lBl[sb]);
        }
        #pragma unroll
        for (int m = 0; m < 4; ++m)
            #pragma unroll
            for (int n = 0; n < 4; ++n) {
                acc[m][n] = __builtin_amdgcn_mfma_f32_16x16x32_bf16(fah[m], fbh[n], acc[m][n], 0, 0, 0);
                acc[m][n] = __builtin_amdgcn_mfma_f32_16x16x32_bf16(fah[m], fbl[n], acc[m][n], 0, 0, 0);
                acc[m][n] = __builtin_amdgcn_mfma_f32_16x16x32_bf16(fal[m], fbh[n], acc[m][n], 0, 0, 0);
            }
    }
    int head = blockIdx.y * 2 + wc;
    long hbase = (long)head * Mpad * 64;
    #pragma unroll
    for (int m = 0; m < 4; ++m)
        #pragma unroll
        for (int j = 0; j < 4; ++j) {
            int gr = r0 + wr * 64 + m * 16 + (lane >> 4) * 4 + j;
            if (gr < M) {
                #pragma unroll
                for (int n = 0; n < 4; ++n)
                    Cc[hbase + (long)gr * 64 + n * 16 + (lane & 15)] = acc[m][n][j];
            }
        }
    // fused attention dots: this wave owns `head` for its 64 rows
    float asv[4], adv[4];
    #pragma unroll
    for (int nn = 0; nn < 4; ++nn) {
        asv[nn] = a_src[head * 64 + nn * 16 + (lane & 15)];
        adv[nn] = a_dst[head * 64 + nn * 16 + (lane & 15)];
    }
    #pragma unroll
    for (int m = 0; m < 4; ++m)
        #pragma unroll
        for (int j = 0; j < 4; ++j) {
            int gr = r0 + wr * 64 + m * 16 + (lane >> 4) * 4 + j;
            float es = 0.f, ed = 0.f;
            #pragma unroll
            for (int nn = 0; nn < 4; ++nn) {
                es = fmaf(acc[m][nn][j], asv[nn], es);
                ed = fmaf(acc[m][nn][j], adv[nn], ed);
            }
            #pragma unroll
            for (int o = 1; o < 16; o <<= 1) {
                es += __shfl_xor(es, o);
                ed += __shfl_xor(ed, o);
            }
            if ((lane & 15) == 0 && gr < M) {
                e_src[gr * 8 + head] = es;
                e_dst[gr * 8 + head] = ed;
            }
        }
}

// ---------------- init h2 output with bias (layer-2 pre-pass) ----------------
__global__ void k_binit(float* __restrict__ out, const float* __restrict__ bias, int total) {
    int i = blockIdx.x * blockDim.x + threadIdx.x;
    if (i >= total) return;
    out[i] = bias[i & 63];
}

// ---------------- per-(dst-node, head) softmax + aggregation ----------------
// grid = (ceil(N/8), H); block = 8 waves; wave = one node, head = blockIdx.y.
// Head-outer dispatch keeps each 5.1MB head-slice of hpre hot in L2.
__global__ __launch_bounds__(512) void k_agg(const float4* __restrict__ hpre4,
                                             const float* __restrict__ e_src,
                                             const float* __restrict__ e_dst,
                                             const int* __restrict__ row_start,
                                             const int* __restrict__ csr_src,
                                             const float* __restrict__ bias,
                                             float* __restrict__ out,
                                             short* __restrict__ h1h,
                                             short* __restrict__ h1l,
                                             float* __restrict__ mbuf,
                                             float* __restrict__ invbuf,
                                             int N, int Mpad, int concat) {
    __shared__ float pbuf[8][64];
    __shared__ int   sbuf[8][64];
    int wid = threadIdx.x >> 6, lane = threadIdx.x & 63;
    int n = blockIdx.x * 8 + wid;
    if (n >= N) return;                 // wave-uniform; no barriers in kernel
    int h = blockIdx.y;
    int eg = lane >> 4;                 // edge subgroup 0..3
    int cq = lane & 15;                 // channel quad 0..15
    long hoff = (long)h * Mpad * 16;    // float4 units
    int row = row_start[n];
    int deg = row_start[n + 1] - row;
    float edst = e_dst[n * 8 + h];
    // pass 1: max
    float m = -3.0e38f;
    for (int i = lane; i < deg; i += 64) {
        int s = csr_src[row + i];
        m = fmaxf(m, leaky(e_src[s * 8 + h] + edst));
    }
    for (int o = 32; o; o >>= 1) m = fmaxf(m, __shfl_xor(m, o));
    // pass 2: p + 4-edge float4 feature gather
    float psum = 0.f;
    float4 acc = make_float4(0.f, 0.f, 0.f, 0.f);
    for (int base = 0; base < deg; base += 64) {
        int i = base + lane;
        float p = 0.f; int s = 0;
        if (i < deg) {
            s = csr_src[row + i];
            p = __expf(leaky(e_src[s * 8 + h] + edst) - m);
        }
        pbuf[wid][lane] = p;
        sbuf[wid][lane] = s;
        psum += p;
        int lim = min(64, deg - base);
        for (int j4 = 0; j4 < lim; j4 += 4) {
            int j = j4 + eg;
            float pj = 0.f; int sj = 0;
            if (j < lim) { pj = pbuf[wid][j]; sj = sbuf[wid][j]; }
            float4 hv = hpre4[hoff + (long)sj * 16 + cq];
            acc.x = fmaf(pj, hv.x, acc.x);
            acc.y = fmaf(pj, hv.y, acc.y);
            acc.z = fmaf(pj, hv.z, acc.z);
            acc.w = fmaf(pj, hv.w, acc.w);
        }
    }
    #pragma unroll
    for (int o = 16; o <= 32; o <<= 1) {
        acc.x += __shfl_xor(acc.x, o);
        acc.y += __shfl_xor(acc.y, o);
        acc.z += __shfl_xor(acc.z, o);
        acc.w += __shfl_xor(acc.w, o);
    }
    for (int o = 32; o; o >>= 1) psum += __shfl_xor(psum, o);
    float inv = 1.0f / psum;
    if (lane == 0) { mbuf[n * 8 + h] = m; invbuf[n * 8 + h] = inv; }
    acc.x *= inv; acc.y *= inv; acc.z *= inv; acc.w *= inv;
    if (concat) {
        if (eg == 0) {
            const float4* bias4 = reinterpret_cast<const float4*>(bias);
            float4 b = bias4[h * 16 + cq];
            float vv[4] = {acc.x + b.x, acc.y + b.y, acc.z + b.z, acc.w + b.w};
            short4v hh, ll;
            #pragma unroll
            for (int k = 0; k < 4; ++k) {
                float v = vv[k] > 0.f ? vv[k] : 0.f;
                short hi = f2bf(v);
                hh[k] = hi;
                ll[k] = f2bf(v - bf2f(hi));
            }
            long o4 = (long)n * 128 + h * 16 + cq;
            reinterpret_cast<short4v*>(h1h)[o4] = hh;
            reinterpret_cast<short4v*>(h1l)[o4] = ll;
        }
    } else {
        if (eg == 0) {
            float* dst = out + (long)n * 64 + cq * 4;
            atomicAdd(dst + 0, acc.x * 0.125f);
            atomicAdd(dst + 1, acc.y * 0.125f);
            atomicAdd(dst + 2, acc.z * 0.125f);
            atomicAdd(dst + 3, acc.w * 0.125f);
        }
    }
}

// ---------------- edge-parallel alpha write (1 thread = 1 edge, all 8 heads) ----------------
__global__ void k_alpha(const int* __restrict__ ei, int E, int N,
                        const float* __restrict__ e_src, const float* __restrict__ e_dst,
                        const float* __restrict__ mbuf, const float* __restrict__ invbuf,
                        float* __restrict__ alpha) {
    int e = blockIdx.x * blockDim.x + threadIdx.x;
    int Et = E + N;
    if (e >= Et) return;
    int s, d;
    if (e < E) { s = ei[e]; d = ei[E + e]; } else { s = d = e - E; }
    const float4* es4 = reinterpret_cast<const float4*>(e_src) + (long)s * 2;
    const float4* ed4 = reinterpret_cast<const float4*>(e_dst) + (long)d * 2;
    const float4* m4  = reinterpret_cast<const float4*>(mbuf) + (long)d * 2;
    const float4* i4  = reinterpret_cast<const float4*>(invbuf) + (long)d * 2;
    float4* out4 = reinterpret_cast<float4*>(alpha) + (long)e * 2;
    #pragma unroll
    for (int q = 0; q < 2; ++q) {
        float4 es = es4[q], ed = ed4[q], mm = m4[q], iv = i4[q];
        float4 r;
        r.x = __expf(leaky(es.x + ed.x) - mm.x) * iv.x;
        r.y = __expf(leaky(es.y + ed.y) - mm.y) * iv.y;
        r.z = __expf(leaky(es.z + ed.z) - mm.z) * iv.z;
        r.w = __expf(leaky(es.w + ed.w) - mm.w) * iv.w;
        out4[q] = r;
    }
}

extern "C" void kernel_launch(void* const* d_in, const int* in_sizes, int n_in,
                              void* d_out, int out_size, void* d_ws, size_t ws_size,
                              hipStream_t stream) {
    const float* x   = (const float*)d_in[0];
    const int*   ei  = (const int*)d_in[1];
    const float* W1  = (const float*)d_in[2];
    const float* as1 = (const float*)d_in[3];
    const float* ad1 = (const float*)d_in[4];
    const float* b1  = (const float*)d_in[5];
    const float* W2  = (const float*)d_in[6];
    const float* as2 = (const float*)d_in[7];
    const float* ad2 = (const float*)d_in[8];
    const float* b2  = (const float*)d_in[9];

    int N  = in_sizes[0] / 256;
    int E  = in_sizes[1] / 2;
    int Et = E + N;
    int K1 = 256;
    int Mb   = (N + 127) / 128;
    int Mpad = Mb * 128;

    float* out    = (float*)d_out;
    float* h2_out = out;
    float* alpha1 = out + (size_t)N * 64;
    float* alpha2 = alpha1 + (size_t)Et * H;

    float* ws     = (float*)d_ws;
    float* hpre   = ws;                                   // [H][Mpad][64] fp32
    short* Ahb    = (short*)(hpre + (size_t)Mpad * HC);   // Mpad*512 bf16
    short* Alb    = Ahb + (size_t)Mpad * HC;
    short* W1th   = Alb + (size_t)Mpad * HC;              // 512*256
    short* W1tl   = W1th + (size_t)HC * K1;
    short* W2th   = W1tl + (size_t)HC * K1;               // 512*512
    short* W2tl   = W2th + (size_t)HC * HC;
    float* eS     = (float*)(W2tl + (size_t)HC * HC);
    float* eD     = eS + (size_t)N * H;
    float* mbuf   = eD + (size_t)N * H;
    float* invbuf = mbuf + (size_t)N * H;
    int*   deg    = (int*)(invbuf + (size_t)N * H);
    int*   cursor = deg + N;
    int*   row_st = cursor + N;
    int*   csr_src= row_st + N + 1;

    hipMemsetAsync(deg, 0, (size_t)2 * N * sizeof(int), stream);
    int tb = 256;
    k_degree<<<(Et + tb - 1) / tb, tb, 0, stream>>>(ei, E, N, deg);
    k_scan<<<1, 1024, 0, stream>>>(deg, N, row_st);
    k_fill<<<(Et + tb - 1) / tb, tb, 0, stream>>>(ei, E, N, row_st, cursor, csr_src);

    int n4 = N * K1 / 4;
    k_split4<<<(n4 + tb - 1) / tb, tb, 0, stream>>>(x, Ahb, Alb, n4);
    k_tsplit<<<(K1 * HC + tb - 1) / tb, tb, 0, stream>>>(W1, W1th, W1tl, K1, HC);
    k_tsplit<<<(HC * HC + tb - 1) / tb, tb, 0, stream>>>(W2, W2th, W2tl, HC, HC);

    dim3 gg(Mb, HC / 128);
    dim3 ga((N + 7) / 8, H);
    // layer 1
    k_gemm_mfma<<<gg, 256, 0, stream>>>(Ahb, Alb, W1th, W1tl, hpre, N, K1, Mpad, as1, ad1, eS, eD);
    k_agg<<<ga, 512, 0, stream>>>((const float4*)hpre, eS, eD, row_st, csr_src, b1, nullptr, Ahb, Alb, mbuf, invbuf, N, Mpad, 1);
    k_alpha<<<(Et + tb - 1) / tb, tb, 0, stream>>>(ei, E, N, eS, eD, mbuf, invbuf, alpha1);
    // layer 2
    k_gemm_mfma<<<gg, 256, 0, stream>>>(Ahb, Alb, W2th, W2tl, hpre, N, HC, Mpad, as2, ad2, eS, eD);
    k_binit<<<(N * 64 + tb - 1) / tb, tb, 0, stream>>>(h2_out, b2, N * 64);
    k_agg<<<ga, 512, 0, stream>>>((const float4*)hpre, eS, eD, row_st, csr_src, b2, h2_out, nullptr, nullptr, mbuf, invbuf, N, Mpad, 0);
    k_alpha<<<(Et + tb - 1) / tb, tb, 0, stream>>>(ei, E, N, eS, eD, mbuf, invbuf, alpha2);
}

// Round 5
// 404.044 us; speedup vs baseline: 1.2000x; 1.2000x over previous
//
#include <hip/hip_runtime.h>

#define H 8
#define C 64
#define HC 512
#define NEG 0.2f

typedef __attribute__((ext_vector_type(8))) short bf16x8;
typedef __attribute__((ext_vector_type(4))) float f32x4;
typedef __attribute__((ext_vector_type(4))) short short4v;
typedef __attribute__((ext_vector_type(8))) short short8v;
typedef __attribute__((ext_vector_type(8))) _Float16 half8v;

__device__ __forceinline__ float leaky(float x) { return x > 0.f ? x : NEG * x; }

__device__ __forceinline__ short f2bf(float x) {
    unsigned u = __float_as_uint(x);
    unsigned r = (u + 0x7fffu + ((u >> 16) & 1u)) >> 16;
    return (short)r;
}
__device__ __forceinline__ float bf2f(short s) {
    return __uint_as_float(((unsigned)(unsigned short)s) << 16);
}

#define GLOAD_LDS16(gp, lp) \
  __builtin_amdgcn_global_load_lds((const __attribute__((address_space(1))) unsigned int*)(gp), \
                                   (__attribute__((address_space(3))) unsigned int*)(lp), 16, 0, 0)

// ---------------- CSR build (dst-sorted) ----------------
__global__ void k_degree(const int* __restrict__ ei, int E, int N, int* __restrict__ deg) {
    int e = blockIdx.x * blockDim.x + threadIdx.x;
    int Et = E + N;
    if (e >= Et) return;
    int d = (e < E) ? ei[E + e] : (e - E);
    atomicAdd(&deg[d], 1);
}

__global__ __launch_bounds__(1024) void k_scan(const int* __restrict__ deg, int N, int* __restrict__ row_start) {
    __shared__ int part[1024];
    int t = threadIdx.x;
    int chunk = (N + 1023) >> 10;
    int lo = t * chunk, hi = min(lo + chunk, N);
    int s = 0;
    for (int i = lo; i < hi; ++i) s += deg[i];
    part[t] = s;
    __syncthreads();
    for (int off = 1; off < 1024; off <<= 1) {
        int v = (t >= off) ? part[t - off] : 0;
        __syncthreads();
        part[t] += v;
        __syncthreads();
    }
    int base = (t == 0) ? 0 : part[t - 1];
    for (int i = lo; i < hi; ++i) { row_start[i] = base; base += deg[i]; }
    if (t == 1023) row_start[N] = part[1023];
}

__global__ void k_fill(const int* __restrict__ ei, int E, int N,
                       const int* __restrict__ row_start, int* __restrict__ cursor,
                       int* __restrict__ csr_src) {
    int e = blockIdx.x * blockDim.x + threadIdx.x;
    int Et = E + N;
    if (e >= Et) return;
    int d, s;
    if (e < E) { s = ei[e]; d = ei[E + e]; } else { s = e - E; d = s; }
    int pos = atomicAdd(&cursor[d], 1);
    csr_src[row_start[d] + pos] = s;
}

// ---------------- split fp32 -> bf16 hi + bf16 lo ----------------
__global__ void k_split4(const float* __restrict__ in, short* __restrict__ hi,
                         short* __restrict__ lo, int n4) {
    int i = blockIdx.x * blockDim.x + threadIdx.x;
    if (i >= n4) return;
    float4 v = reinterpret_cast<const float4*>(in)[i];
    short4v h, l;
    float vv[4] = {v.x, v.y, v.z, v.w};
    #pragma unroll
    for (int j = 0; j < 4; ++j) {
        short hh = f2bf(vv[j]);
        h[j] = hh;
        l[j] = f2bf(vv[j] - bf2f(hh));
    }
    reinterpret_cast<short4v*>(hi)[i] = h;
    reinterpret_cast<short4v*>(lo)[i] = l;
}

// W [K][Nc] fp32 -> Wt hi/lo [Nc][K] bf16
__global__ void k_tsplit(const float* __restrict__ W, short* __restrict__ th,
                         short* __restrict__ tl, int K, int Nc) {
    int idx = blockIdx.x * blockDim.x + threadIdx.x;
    if (idx >= K * Nc) return;
    int c = idx / K, k = idx - c * K;
    float v = W[(long)k * Nc + c];
    short hh = f2bf(v);
    th[idx] = hh;
    tl[idx] = f2bf(v - bf2f(hh));
}

// ---------------- MFMA GEMM + fused attention-dot epilogue ----------------
// hpre written HEAD-MAJOR fp16: hpre[head][Mpad][64]. 3-pass split bf16 MFMA.
__global__ __launch_bounds__(256) void k_gemm_mfma(const short* __restrict__ Ah, const short* __restrict__ Al,
                                                   const short* __restrict__ Bh, const short* __restrict__ Bl,
                                                   _Float16* __restrict__ Cc, int M, int K, int Mpad,
                                                   const float* __restrict__ a_src, const float* __restrict__ a_dst,
                                                   float* __restrict__ e_src, float* __restrict__ e_dst) {
    __shared__ short lAh[4096], lAl[4096], lBh[4096], lBl[4096];
    int tid = threadIdx.x;
    int w = tid >> 6, lane = tid & 63;
    int wr = w >> 1, wc = w & 1;
    int r0 = blockIdx.x * 128, c0 = blockIdx.y * 128;
    f32x4 acc[4][4] = {};
    int frag_off = ((lane >> 4) * 16 + (lane & 15)) * 8;

    for (int k0 = 0; k0 < K; k0 += 32) {
        __syncthreads();
        #pragma unroll
        for (int it = 0; it < 2; ++it) {
            int slot = it * 256 + tid;
            int rb = slot >> 6, kc = (slot >> 4) & 3, r16 = slot & 15;
            long ga = (long)(r0 + rb * 16 + r16) * K + k0 + kc * 8;
            long gb = (long)(c0 + rb * 16 + r16) * K + k0 + kc * 8;
            int ldst = (it * 256 + w * 64) * 8;
            GLOAD_LDS16(Ah + ga, lAh + ldst);
            GLOAD_LDS16(Al + ga, lAl + ldst);
            GLOAD_LDS16(Bh + gb, lBh + ldst);
            GLOAD_LDS16(Bl + gb, lBl + ldst);
        }
        __syncthreads();
        bf16x8 fah[4], fal[4], fbh[4], fbl[4];
        #pragma unroll
        for (int m = 0; m < 4; ++m) {
            int sa = (wr * 4 + m) * 512 + frag_off;
            fah[m] = *reinterpret_cast<bf16x8*>(&lAh[sa]);
            fal[m] = *reinterpret_cast<bf16x8*>(&lAl[sa]);
            int sb = (wc * 4 + m) * 512 + frag_off;
            fbh[m] = *reinterpret_cast<bf16x8*>(&lBh[sb]);
            fbl[m] = *reinterpret_cast<bf16x8*>(&lBl[sb]);
        }
        #pragma unroll
        for (int m = 0; m < 4; ++m)
            #pragma unroll
            for (int n = 0; n < 4; ++n) {
                acc[m][n] = __builtin_amdgcn_mfma_f32_16x16x32_bf16(fah[m], fbh[n], acc[m][n], 0, 0, 0);
                acc[m][n] = __builtin_amdgcn_mfma_f32_16x16x32_bf16(fah[m], fbl[n], acc[m][n], 0, 0, 0);
                acc[m][n] = __builtin_amdgcn_mfma_f32_16x16x32_bf16(fal[m], fbh[n], acc[m][n], 0, 0, 0);
            }
    }
    int head = blockIdx.y * 2 + wc;
    long hbase = (long)head * Mpad * 64;
    #pragma unroll
    for (int m = 0; m < 4; ++m)
        #pragma unroll
        for (int j = 0; j < 4; ++j) {
            int gr = r0 + wr * 64 + m * 16 + (lane >> 4) * 4 + j;
            if (gr < M) {
                #pragma unroll
                for (int n = 0; n < 4; ++n)
                    Cc[hbase + (long)gr * 64 + n * 16 + (lane & 15)] = (_Float16)acc[m][n][j];
            }
        }
    // fused attention dots
    float asv[4], adv[4];
    #pragma unroll
    for (int nn = 0; nn < 4; ++nn) {
        asv[nn] = a_src[head * 64 + nn * 16 + (lane & 15)];
        adv[nn] = a_dst[head * 64 + nn * 16 + (lane & 15)];
    }
    #pragma unroll
    for (int m = 0; m < 4; ++m)
        #pragma unroll
        for (int j = 0; j < 4; ++j) {
            int gr = r0 + wr * 64 + m * 16 + (lane >> 4) * 4 + j;
            float es = 0.f, ed = 0.f;
            #pragma unroll
            for (int nn = 0; nn < 4; ++nn) {
                es = fmaf(acc[m][nn][j], asv[nn], es);
                ed = fmaf(acc[m][nn][j], adv[nn], ed);
            }
            #pragma unroll
            for (int o = 1; o < 16; o <<= 1) {
                es += __shfl_xor(es, o);
                ed += __shfl_xor(ed, o);
            }
            if ((lane & 15) == 0 && gr < M) {
                e_src[gr * 8 + head] = es;
                e_dst[gr * 8 + head] = ed;
            }
        }
}

// ---------------- per-(dst-node, head) softmax + aggregation ----------------
// 1-D grid, h = blockIdx.x & 7 -> all blocks of head h land on one XCD
// (round-robin dispatch heuristic), whose L2 holds that head's 2.57MB slice.
// wave = one node; 8 edge subgroups x 8 channel lanes; half8 (16B) gathers.
__global__ __launch_bounds__(512) void k_agg(const half8v* __restrict__ hpre8,
                                             const float* __restrict__ e_src,
                                             const float* __restrict__ e_dst,
                                             const int* __restrict__ row_start,
                                             const int* __restrict__ csr_src,
                                             const float* __restrict__ bias,
                                             _Float16* __restrict__ accq,
                                             short* __restrict__ h1h,
                                             short* __restrict__ h1l,
                                             float* __restrict__ mbuf,
                                             float* __restrict__ invbuf,
                                             int N, int Mpad, int concat) {
    __shared__ float pbuf[8][64];
    __shared__ int   sbuf[8][64];
    int wid = threadIdx.x >> 6, lane = threadIdx.x & 63;
    int h  = blockIdx.x & 7;
    int nb = blockIdx.x >> 3;
    int n = nb * 8 + wid;
    if (n >= N) return;                 // wave-uniform; no block barriers used
    int eg = lane >> 3;                 // edge subgroup 0..7
    int cg = lane & 7;                  // channel group (8 halfs each)
    long hoff8 = (long)h * Mpad * 8;    // half8 units per head slice
    int row = row_start[n];
    int deg = row_start[n + 1] - row;
    float edst = e_dst[n * 8 + h];
    // pass 1: max
    float m = -3.0e38f;
    for (int i = lane; i < deg; i += 64) {
        int s = csr_src[row + i];
        m = fmaxf(m, leaky(e_src[s * 8 + h] + edst));
    }
    for (int o = 32; o; o >>= 1) m = fmaxf(m, __shfl_xor(m, o));
    // pass 2: p + 8-edge half8 feature gather
    float psum = 0.f;
    float acc8[8] = {};
    for (int base = 0; base < deg; base += 64) {
        int i = base + lane;
        float p = 0.f; int s = 0;
        if (i < deg) {
            s = csr_src[row + i];
            p = __expf(leaky(e_src[s * 8 + h] + edst) - m);
        }
        pbuf[wid][lane] = p;
        sbuf[wid][lane] = s;
        psum += p;
        int lim = min(64, deg - base);
        for (int j8 = 0; j8 < lim; j8 += 8) {
            int j = j8 + eg;
            float pj = 0.f; int sj = 0;
            if (j < lim) { pj = pbuf[wid][j]; sj = sbuf[wid][j]; }
            half8v hv = hpre8[hoff8 + (long)sj * 8 + cg];
            #pragma unroll
            for (int k = 0; k < 8; ++k)
                acc8[k] = fmaf((float)hv[k], pj, acc8[k]);  // v_fma_mix_f32 expected
        }
    }
    // reduce across 8 edge subgroups (stride 8,16,32)
    #pragma unroll
    for (int o = 8; o <= 32; o <<= 1)
        #pragma unroll
        for (int k = 0; k < 8; ++k)
            acc8[k] += __shfl_xor(acc8[k], o);
    for (int o = 32; o; o >>= 1) psum += __shfl_xor(psum, o);
    float inv = 1.0f / psum;
    if (lane == 0) { mbuf[n * 8 + h] = m; invbuf[n * 8 + h] = inv; }
    if (eg == 0) {   // lanes 0..7 hold the final 64-channel result
        if (concat) {
            short8v hh, ll;
            #pragma unroll
            for (int k = 0; k < 8; ++k) {
                float v = acc8[k] * inv + bias[h * 64 + cg * 8 + k];
                v = v > 0.f ? v : 0.f;
                short hb = f2bf(v);
                hh[k] = hb;
                ll[k] = f2bf(v - bf2f(hb));
            }
            long o8 = (long)n * 64 + h * 8 + cg;   // short8 units, node-major [n][512]
            reinterpret_cast<short8v*>(h1h)[o8] = hh;
            reinterpret_cast<short8v*>(h1l)[o8] = ll;
        } else {
            half8v hv;
            #pragma unroll
            for (int k = 0; k < 8; ++k) hv[k] = (_Float16)(acc8[k] * inv);
            reinterpret_cast<half8v*>(accq)[hoff8 + (long)n * 8 + cg] = hv;
        }
    }
}

// ---------------- mean over heads + bias (layer 2 finish) ----------------
__global__ void k_mean(const _Float16* __restrict__ accq, const float* __restrict__ bias,
                       float* __restrict__ out, int N, int Mpad) {
    int i = blockIdx.x * blockDim.x + threadIdx.x;
    if (i >= N * 64) return;
    int n = i >> 6, c = i & 63;
    float s = 0.f;
    #pragma unroll
    for (int h = 0; h < 8; ++h)
        s += (float)accq[(long)h * Mpad * 64 + (long)n * 64 + c];
    out[i] = s * 0.125f + bias[c];
}

// ---------------- edge-parallel alpha write (1 thread = 1 edge, 8 heads) ----------------
__global__ void k_alpha(const int* __restrict__ ei, int E, int N,
                        const float* __restrict__ e_src, const float* __restrict__ e_dst,
                        const float* __restrict__ mbuf, const float* __restrict__ invbuf,
                        float* __restrict__ alpha) {
    int e = blockIdx.x * blockDim.x + threadIdx.x;
    int Et = E + N;
    if (e >= Et) return;
    int s, d;
    if (e < E) { s = ei[e]; d = ei[E + e]; } else { s = d = e - E; }
    const float4* es4 = reinterpret_cast<const float4*>(e_src) + (long)s * 2;
    const float4* ed4 = reinterpret_cast<const float4*>(e_dst) + (long)d * 2;
    const float4* m4  = reinterpret_cast<const float4*>(mbuf) + (long)d * 2;
    const float4* i4  = reinterpret_cast<const float4*>(invbuf) + (long)d * 2;
    float4* out4 = reinterpret_cast<float4*>(alpha) + (long)e * 2;
    #pragma unroll
    for (int q = 0; q < 2; ++q) {
        float4 es = es4[q], ed = ed4[q], mm = m4[q], iv = i4[q];
        float4 r;
        r.x = __expf(leaky(es.x + ed.x) - mm.x) * iv.x;
        r.y = __expf(leaky(es.y + ed.y) - mm.y) * iv.y;
        r.z = __expf(leaky(es.z + ed.z) - mm.z) * iv.z;
        r.w = __expf(leaky(es.w + ed.w) - mm.w) * iv.w;
        out4[q] = r;
    }
}

extern "C" void kernel_launch(void* const* d_in, const int* in_sizes, int n_in,
                              void* d_out, int out_size, void* d_ws, size_t ws_size,
                              hipStream_t stream) {
    const float* x   = (const float*)d_in[0];
    const int*   ei  = (const int*)d_in[1];
    const float* W1  = (const float*)d_in[2];
    const float* as1 = (const float*)d_in[3];
    const float* ad1 = (const float*)d_in[4];
    const float* b1  = (const float*)d_in[5];
    const float* W2  = (const float*)d_in[6];
    const float* as2 = (const float*)d_in[7];
    const float* ad2 = (const float*)d_in[8];
    const float* b2  = (const float*)d_in[9];

    int N  = in_sizes[0] / 256;
    int E  = in_sizes[1] / 2;
    int Et = E + N;
    int K1 = 256;
    int Mb   = (N + 127) / 128;
    int Mpad = Mb * 128;

    float* out    = (float*)d_out;
    float* h2_out = out;
    float* alpha1 = out + (size_t)N * 64;
    float* alpha2 = alpha1 + (size_t)Et * H;

    _Float16* hpre = (_Float16*)d_ws;                      // [H][Mpad][64] fp16
    _Float16* accq = hpre + (size_t)H * Mpad * 64;         // [H][Mpad][64] fp16
    short* Ahb    = (short*)(accq + (size_t)H * Mpad * 64);// Mpad*512 bf16
    short* Alb    = Ahb + (size_t)Mpad * HC;
    short* W1th   = Alb + (size_t)Mpad * HC;               // 512*256
    short* W1tl   = W1th + (size_t)HC * K1;
    short* W2th   = W1tl + (size_t)HC * K1;                // 512*512
    short* W2tl   = W2th + (size_t)HC * HC;
    float* eS     = (float*)(W2tl + (size_t)HC * HC);
    float* eD     = eS + (size_t)N * H;
    float* mbuf   = eD + (size_t)N * H;
    float* invbuf = mbuf + (size_t)N * H;
    int*   deg    = (int*)(invbuf + (size_t)N * H);
    int*   cursor = deg + N;
    int*   row_st = cursor + N;
    int*   csr_src= row_st + N + 1;

    hipMemsetAsync(deg, 0, (size_t)2 * N * sizeof(int), stream);
    int tb = 256;
    k_degree<<<(Et + tb - 1) / tb, tb, 0, stream>>>(ei, E, N, deg);
    k_scan<<<1, 1024, 0, stream>>>(deg, N, row_st);
    k_fill<<<(Et + tb - 1) / tb, tb, 0, stream>>>(ei, E, N, row_st, cursor, csr_src);

    int n4 = N * K1 / 4;
    k_split4<<<(n4 + tb - 1) / tb, tb, 0, stream>>>(x, Ahb, Alb, n4);
    k_tsplit<<<(K1 * HC + tb - 1) / tb, tb, 0, stream>>>(W1, W1th, W1tl, K1, HC);
    k_tsplit<<<(HC * HC + tb - 1) / tb, tb, 0, stream>>>(W2, W2th, W2tl, HC, HC);

    dim3 gg(Mb, HC / 128);
    int gagg = ((N + 7) / 8) * 8;   // 1-D: low 3 bits = head (XCD affinity)
    // layer 1
    k_gemm_mfma<<<gg, 256, 0, stream>>>(Ahb, Alb, W1th, W1tl, hpre, N, K1, Mpad, as1, ad1, eS, eD);
    k_agg<<<gagg, 512, 0, stream>>>((const half8v*)hpre, eS, eD, row_st, csr_src, b1, nullptr, Ahb, Alb, mbuf, invbuf, N, Mpad, 1);
    k_alpha<<<(Et + tb - 1) / tb, tb, 0, stream>>>(ei, E, N, eS, eD, mbuf, invbuf, alpha1);
    // layer 2
    k_gemm_mfma<<<gg, 256, 0, stream>>>(Ahb, Alb, W2th, W2tl, hpre, N, HC, Mpad, as2, ad2, eS, eD);
    k_agg<<<gagg, 512, 0, stream>>>((const half8v*)hpre, eS, eD, row_st, csr_src, b2, accq, nullptr, nullptr, mbuf, invbuf, N, Mpad, 0);
    k_mean<<<(N * 64 + tb - 1) / tb, tb, 0, stream>>>(accq, b2, h2_out, N, Mpad);
    k_alpha<<<(Et + tb - 1) / tb, tb, 0, stream>>>(ei, E, N, eS, eD, mbuf, invbuf, alpha2);
}

// Round 6
// 309.091 us; speedup vs baseline: 1.5687x; 1.3072x over previous
//
#include <hip/hip_runtime.h>

#define H 8
#define C 64
#define HC 512
#define NEG 0.2f

typedef __attribute__((ext_vector_type(8))) short bf16x8;
typedef __attribute__((ext_vector_type(4))) float f32x4;
typedef __attribute__((ext_vector_type(4))) short short4v;
typedef __attribute__((ext_vector_type(8))) short short8v;
typedef __attribute__((ext_vector_type(8))) _Float16 half8v;

__device__ __forceinline__ float leaky(float x) { return x > 0.f ? x : NEG * x; }

__device__ __forceinline__ short f2bf(float x) {
    unsigned u = __float_as_uint(x);
    unsigned r = (u + 0x7fffu + ((u >> 16) & 1u)) >> 16;
    return (short)r;
}
__device__ __forceinline__ float bf2f(short s) {
    return __uint_as_float(((unsigned)(unsigned short)s) << 16);
}

#define GLOAD_LDS16(gp, lp) \
  __builtin_amdgcn_global_load_lds((const __attribute__((address_space(1))) unsigned int*)(gp), \
                                   (__attribute__((address_space(3))) unsigned int*)(lp), 16, 0, 0)

// ---------------- CSR build (dst-sorted) ----------------
__global__ void k_degree(const int* __restrict__ ei, int E, int N, int* __restrict__ deg) {
    int e = blockIdx.x * blockDim.x + threadIdx.x;
    int Et = E + N;
    if (e >= Et) return;
    int d = (e < E) ? ei[E + e] : (e - E);
    atomicAdd(&deg[d], 1);
}

__global__ __launch_bounds__(1024) void k_scan(const int* __restrict__ deg, int N, int* __restrict__ row_start) {
    __shared__ int part[1024];
    int t = threadIdx.x;
    int chunk = (N + 1023) >> 10;
    int lo = t * chunk, hi = min(lo + chunk, N);
    int s = 0;
    for (int i = lo; i < hi; ++i) s += deg[i];
    part[t] = s;
    __syncthreads();
    for (int off = 1; off < 1024; off <<= 1) {
        int v = (t >= off) ? part[t - off] : 0;
        __syncthreads();
        part[t] += v;
        __syncthreads();
    }
    int base = (t == 0) ? 0 : part[t - 1];
    for (int i = lo; i < hi; ++i) { row_start[i] = base; base += deg[i]; }
    if (t == 1023) row_start[N] = part[1023];
}

__global__ void k_fill(const int* __restrict__ ei, int E, int N,
                       const int* __restrict__ row_start, int* __restrict__ cursor,
                       int* __restrict__ csr_src, int* __restrict__ csr_eid) {
    int e = blockIdx.x * blockDim.x + threadIdx.x;
    int Et = E + N;
    if (e >= Et) return;
    int d, s;
    if (e < E) { s = ei[e]; d = ei[E + e]; } else { s = e - E; d = s; }
    int pos = atomicAdd(&cursor[d], 1);
    int idx = row_start[d] + pos;
    csr_src[idx] = s;
    csr_eid[idx] = e;
}

// ---------------- split fp32 -> bf16 hi + bf16 lo ----------------
__global__ void k_split4(const float* __restrict__ in, short* __restrict__ hi,
                         short* __restrict__ lo, int n4) {
    int i = blockIdx.x * blockDim.x + threadIdx.x;
    if (i >= n4) return;
    float4 v = reinterpret_cast<const float4*>(in)[i];
    short4v h, l;
    float vv[4] = {v.x, v.y, v.z, v.w};
    #pragma unroll
    for (int j = 0; j < 4; ++j) {
        short hh = f2bf(vv[j]);
        h[j] = hh;
        l[j] = f2bf(vv[j] - bf2f(hh));
    }
    reinterpret_cast<short4v*>(hi)[i] = h;
    reinterpret_cast<short4v*>(lo)[i] = l;
}

// W [K][Nc] fp32 -> Wt hi/lo [Nc][K] bf16
__global__ void k_tsplit(const float* __restrict__ W, short* __restrict__ th,
                         short* __restrict__ tl, int K, int Nc) {
    int idx = blockIdx.x * blockDim.x + threadIdx.x;
    if (idx >= K * Nc) return;
    int c = idx / K, k = idx - c * K;
    float v = W[(long)k * Nc + c];
    short hh = f2bf(v);
    th[idx] = hh;
    tl[idx] = f2bf(v - bf2f(hh));
}

// ---------------- MFMA GEMM + fused attention-dot epilogue ----------------
// hpre written NODE-MAJOR fp16: hpre[Mpad][512] (head*64+ch inner).
__global__ __launch_bounds__(256) void k_gemm_mfma(const short* __restrict__ Ah, const short* __restrict__ Al,
                                                   const short* __restrict__ Bh, const short* __restrict__ Bl,
                                                   _Float16* __restrict__ Cc, int M, int K,
                                                   const float* __restrict__ a_src, const float* __restrict__ a_dst,
                                                   float* __restrict__ e_src, float* __restrict__ e_dst) {
    __shared__ short lAh[4096], lAl[4096], lBh[4096], lBl[4096];
    int tid = threadIdx.x;
    int w = tid >> 6, lane = tid & 63;
    int wr = w >> 1, wc = w & 1;
    int r0 = blockIdx.x * 128, c0 = blockIdx.y * 128;
    f32x4 acc[4][4] = {};
    int frag_off = ((lane >> 4) * 16 + (lane & 15)) * 8;

    for (int k0 = 0; k0 < K; k0 += 32) {
        __syncthreads();
        #pragma unroll
        for (int it = 0; it < 2; ++it) {
            int slot = it * 256 + tid;
            int rb = slot >> 6, kc = (slot >> 4) & 3, r16 = slot & 15;
            long ga = (long)(r0 + rb * 16 + r16) * K + k0 + kc * 8;
            long gb = (long)(c0 + rb * 16 + r16) * K + k0 + kc * 8;
            int ldst = (it * 256 + w * 64) * 8;
            GLOAD_LDS16(Ah + ga, lAh + ldst);
            GLOAD_LDS16(Al + ga, lAl + ldst);
            GLOAD_LDS16(Bh + gb, lBh + ldst);
            GLOAD_LDS16(Bl + gb, lBl + ldst);
        }
        __syncthreads();
        bf16x8 fah[4], fal[4], fbh[4], fbl[4];
        #pragma unroll
        for (int m = 0; m < 4; ++m) {
            int sa = (wr * 4 + m) * 512 + frag_off;
            fah[m] = *reinterpret_cast<bf16x8*>(&lAh[sa]);
            fal[m] = *reinterpret_cast<bf16x8*>(&lAl[sa]);
            int sb = (wc * 4 + m) * 512 + frag_off;
            fbh[m] = *reinterpret_cast<bf16x8*>(&lBh[sb]);
            fbl[m] = *reinterpret_cast<bf16x8*>(&lBl[sb]);
        }
        #pragma unroll
        for (int m = 0; m < 4; ++m)
            #pragma unroll
            for (int n = 0; n < 4; ++n) {
                acc[m][n] = __builtin_amdgcn_mfma_f32_16x16x32_bf16(fah[m], fbh[n], acc[m][n], 0, 0, 0);
                acc[m][n] = __builtin_amdgcn_mfma_f32_16x16x32_bf16(fah[m], fbl[n], acc[m][n], 0, 0, 0);
                acc[m][n] = __builtin_amdgcn_mfma_f32_16x16x32_bf16(fal[m], fbh[n], acc[m][n], 0, 0, 0);
            }
    }
    int head = blockIdx.y * 2 + wc;
    #pragma unroll
    for (int m = 0; m < 4; ++m)
        #pragma unroll
        for (int j = 0; j < 4; ++j) {
            int gr = r0 + wr * 64 + m * 16 + (lane >> 4) * 4 + j;
            if (gr < M) {
                #pragma unroll
                for (int n = 0; n < 4; ++n)
                    Cc[(long)gr * HC + head * 64 + n * 16 + (lane & 15)] = (_Float16)acc[m][n][j];
            }
        }
    // fused attention dots
    float asv[4], adv[4];
    #pragma unroll
    for (int nn = 0; nn < 4; ++nn) {
        asv[nn] = a_src[head * 64 + nn * 16 + (lane & 15)];
        adv[nn] = a_dst[head * 64 + nn * 16 + (lane & 15)];
    }
    #pragma unroll
    for (int m = 0; m < 4; ++m)
        #pragma unroll
        for (int j = 0; j < 4; ++j) {
            int gr = r0 + wr * 64 + m * 16 + (lane >> 4) * 4 + j;
            float es = 0.f, ed = 0.f;
            #pragma unroll
            for (int nn = 0; nn < 4; ++nn) {
                es = fmaf(acc[m][nn][j], asv[nn], es);
                ed = fmaf(acc[m][nn][j], adv[nn], ed);
            }
            #pragma unroll
            for (int o = 1; o < 16; o <<= 1) {
                es += __shfl_xor(es, o);
                ed += __shfl_xor(ed, o);
            }
            if ((lane & 15) == 0 && gr < M) {
                e_src[gr * 8 + head] = es;
                e_dst[gr * 8 + head] = ed;
            }
        }
}

// ---------------- per-node softmax + aggregation + alpha (all 8 heads) ----------------
// One wave per node. P-layout: lane = eg*8 + h (eg=lane>>3, h=lane&7).
// Gather layout: lane = h*8 + cg -> hpre offset = lane*16B (full 1KB node line).
// No max-subtraction: e bounded (|e|<~4), softmax shift-invariant.
__global__ __launch_bounds__(512) void k_agg(const half8v* __restrict__ hp8,
                                             const float* __restrict__ e_src,
                                             const float* __restrict__ e_dst,
                                             const int* __restrict__ row_start,
                                             const int* __restrict__ csr_src,
                                             const int* __restrict__ csr_eid,
                                             const float* __restrict__ bias,
                                             float* __restrict__ h2out,
                                             short* __restrict__ h1h,
                                             short* __restrict__ h1l,
                                             float* __restrict__ alpha,
                                             int N, int concat) {
    __shared__ float pbuf[8][512];     // [wave][edge(64)][head(8)]
    int wid = threadIdx.x >> 6, lane = threadIdx.x & 63;
    int n = blockIdx.x * 8 + wid;
    if (n >= N) return;                // wave-uniform, no block barriers
    int lo3 = lane & 7, hi3 = lane >> 3;
    int row = row_start[n];
    int deg = row_start[n + 1] - row;
    int chunks = (deg + 7) >> 3;
    bool small = (deg <= 64);
    float* pw = &pbuf[wid][0];
    float ed = e_dst[n * 8 + lo3];     // my head (P-layout) = lo3
    // P1: psum over all edges, p cached in LDS when deg<=64
    float psum = 0.f;
    for (int c = 0; c < chunks; ++c) {
        int idx = row + min(c * 8 + lo3, deg - 1);
        int sraw = csr_src[idx];
        int sv = __shfl(sraw, hi3);    // src of my edge (eg = hi3)
        float es = e_src[sv * 8 + lo3];
        float p = __expf(leaky(es + ed));
        if (c * 8 + hi3 >= deg) p = 0.f;
        psum += p;
        if (small) pw[c * 64 + lane] = p;
    }
    psum += __shfl_xor(psum, 8);
    psum += __shfl_xor(psum, 16);
    psum += __shfl_xor(psum, 32);
    float inv = 1.0f / psum;           // per-lane: inv for head lo3
    // P2: alpha write + feature gather
    float acc[8] = {};
    for (int c = 0; c < chunks; ++c) {
        int idx = row + min(c * 8 + lo3, deg - 1);
        int sraw = csr_src[idx];
        int eidr = csr_eid[idx];
        float p;
        if (small) {
            p = pw[c * 64 + lane];
        } else {
            int sv = __shfl(sraw, hi3);
            float es = e_src[sv * 8 + lo3];
            p = __expf(leaky(es + ed));
            if (c * 8 + hi3 >= deg) p = 0.f;
        }
        int eid = __shfl(eidr, hi3);
        if (c * 8 + hi3 < deg)
            alpha[(long)eid * 8 + lo3] = p * inv;
        #pragma unroll
        for (int eg = 0; eg < 8; ++eg) {
            float pe = __shfl(p, eg * 8 + hi3);   // p(edge eg, head hi3)
            int   se = __shfl(sraw, eg);          // src of edge eg
            half8v hv = hp8[(long)se * 64 + lane];
            #pragma unroll
            for (int k = 0; k < 8; ++k)
                acc[k] = fmaf((float)hv[k], pe, acc[k]);
        }
    }
    float invg = __shfl(inv, hi3);     // inv for my gather-head hi3
    if (concat) {
        const float4* b4 = reinterpret_cast<const float4*>(bias);
        float4 ba = b4[lane * 2], bb = b4[lane * 2 + 1];
        float bv[8] = {ba.x, ba.y, ba.z, ba.w, bb.x, bb.y, bb.z, bb.w};
        short8v hh, ll;
        #pragma unroll
        for (int k = 0; k < 8; ++k) {
            float v = fmaf(acc[k], invg, bv[k]);
            v = v > 0.f ? v : 0.f;
            short hb = f2bf(v);
            hh[k] = hb;
            ll[k] = f2bf(v - bf2f(hb));
        }
        reinterpret_cast<short8v*>(h1h)[(long)n * 64 + lane] = hh;
        reinterpret_cast<short8v*>(h1l)[(long)n * 64 + lane] = ll;
    } else {
        float sc = invg * 0.125f;
        #pragma unroll
        for (int k = 0; k < 8; ++k) acc[k] *= sc;
        #pragma unroll
        for (int o = 8; o <= 32; o <<= 1)
            #pragma unroll
            for (int k = 0; k < 8; ++k)
                acc[k] += __shfl_xor(acc[k], o);
        if (hi3 == 0) {                 // lanes 0..7 write 32B each
            float4 r0, r1;
            r0.x = acc[0] + bias[lo3 * 8 + 0];
            r0.y = acc[1] + bias[lo3 * 8 + 1];
            r0.z = acc[2] + bias[lo3 * 8 + 2];
            r0.w = acc[3] + bias[lo3 * 8 + 3];
            r1.x = acc[4] + bias[lo3 * 8 + 4];
            r1.y = acc[5] + bias[lo3 * 8 + 5];
            r1.z = acc[6] + bias[lo3 * 8 + 6];
            r1.w = acc[7] + bias[lo3 * 8 + 7];
            float4* o4 = reinterpret_cast<float4*>(h2out + (long)n * 64 + lo3 * 8);
            o4[0] = r0;
            o4[1] = r1;
        }
    }
}

extern "C" void kernel_launch(void* const* d_in, const int* in_sizes, int n_in,
                              void* d_out, int out_size, void* d_ws, size_t ws_size,
                              hipStream_t stream) {
    const float* x   = (const float*)d_in[0];
    const int*   ei  = (const int*)d_in[1];
    const float* W1  = (const float*)d_in[2];
    const float* as1 = (const float*)d_in[3];
    const float* ad1 = (const float*)d_in[4];
    const float* b1  = (const float*)d_in[5];
    const float* W2  = (const float*)d_in[6];
    const float* as2 = (const float*)d_in[7];
    const float* ad2 = (const float*)d_in[8];
    const float* b2  = (const float*)d_in[9];

    int N  = in_sizes[0] / 256;
    int E  = in_sizes[1] / 2;
    int Et = E + N;
    int K1 = 256;
    int Mb   = (N + 127) / 128;
    int Mpad = Mb * 128;

    float* out    = (float*)d_out;
    float* h2_out = out;
    float* alpha1 = out + (size_t)N * 64;
    float* alpha2 = alpha1 + (size_t)Et * H;

    _Float16* hpre = (_Float16*)d_ws;                      // [Mpad][512] fp16 node-major
    short* Ahb    = (short*)(hpre + (size_t)Mpad * HC);    // [Mpad][512] bf16
    short* Alb    = Ahb + (size_t)Mpad * HC;
    short* W1th   = Alb + (size_t)Mpad * HC;               // 512*256
    short* W1tl   = W1th + (size_t)HC * K1;
    short* W2th   = W1tl + (size_t)HC * K1;                // 512*512
    short* W2tl   = W2th + (size_t)HC * HC;
    float* eS     = (float*)(W2tl + (size_t)HC * HC);      // [N][8]
    float* eD     = eS + (size_t)N * H;
    int*   deg    = (int*)(eD + (size_t)N * H);
    int*   cursor = deg + N;
    int*   row_st = cursor + N;
    int*   csr_src= row_st + N + 1;                        // Et
    int*   csr_eid= csr_src + Et;                          // Et

    hipMemsetAsync(deg, 0, (size_t)2 * N * sizeof(int), stream);
    int tb = 256;
    k_degree<<<(Et + tb - 1) / tb, tb, 0, stream>>>(ei, E, N, deg);
    k_scan<<<1, 1024, 0, stream>>>(deg, N, row_st);
    k_fill<<<(Et + tb - 1) / tb, tb, 0, stream>>>(ei, E, N, row_st, cursor, csr_src, csr_eid);

    int n4 = N * K1 / 4;
    k_split4<<<(n4 + tb - 1) / tb, tb, 0, stream>>>(x, Ahb, Alb, n4);
    k_tsplit<<<(K1 * HC + tb - 1) / tb, tb, 0, stream>>>(W1, W1th, W1tl, K1, HC);
    k_tsplit<<<(HC * HC + tb - 1) / tb, tb, 0, stream>>>(W2, W2th, W2tl, HC, HC);

    dim3 gg(Mb, HC / 128);
    int gagg = (N + 7) / 8;
    // layer 1
    k_gemm_mfma<<<gg, 256, 0, stream>>>(Ahb, Alb, W1th, W1tl, hpre, N, K1, as1, ad1, eS, eD);
    k_agg<<<gagg, 512, 0, stream>>>((const half8v*)hpre, eS, eD, row_st, csr_src, csr_eid,
                                    b1, nullptr, Ahb, Alb, alpha1, N, 1);
    // layer 2
    k_gemm_mfma<<<gg, 256, 0, stream>>>(Ahb, Alb, W2th, W2tl, hpre, N, HC, as2, ad2, eS, eD);
    k_agg<<<gagg, 512, 0, stream>>>((const half8v*)hpre, eS, eD, row_st, csr_src, csr_eid,
                                    b2, h2_out, nullptr, nullptr, alpha2, N, 0);
}

// Round 7
// 274.685 us; speedup vs baseline: 1.7651x; 1.1253x over previous
//
#include <hip/hip_runtime.h>

#define H 8
#define C 64
#define HC 512
#define NEG 0.2f

typedef __attribute__((ext_vector_type(8))) _Float16 half8v;
typedef __attribute__((ext_vector_type(4))) _Float16 half4v;
typedef __attribute__((ext_vector_type(4))) float f32x4;

__device__ __forceinline__ float leaky(float x) { return x > 0.f ? x : NEG * x; }

#define GLOAD_LDS16(gp, lp) \
  __builtin_amdgcn_global_load_lds((const __attribute__((address_space(1))) unsigned int*)(gp), \
                                   (__attribute__((address_space(3))) unsigned int*)(lp), 16, 0, 0)

// ---------------- CSR build (dst-sorted) ----------------
__global__ void k_degree(const int* __restrict__ ei, int E, int N, int* __restrict__ deg) {
    int e = blockIdx.x * blockDim.x + threadIdx.x;
    int Et = E + N;
    if (e >= Et) return;
    int d = (e < E) ? ei[E + e] : (e - E);
    atomicAdd(&deg[d], 1);
}

__global__ __launch_bounds__(1024) void k_scan(const int* __restrict__ deg, int N, int* __restrict__ row_start) {
    __shared__ int part[1024];
    int t = threadIdx.x;
    int chunk = (N + 1023) >> 10;
    int lo = t * chunk, hi = min(lo + chunk, N);
    int s = 0;
    for (int i = lo; i < hi; ++i) s += deg[i];
    part[t] = s;
    __syncthreads();
    for (int off = 1; off < 1024; off <<= 1) {
        int v = (t >= off) ? part[t - off] : 0;
        __syncthreads();
        part[t] += v;
        __syncthreads();
    }
    int base = (t == 0) ? 0 : part[t - 1];
    for (int i = lo; i < hi; ++i) { row_start[i] = base; base += deg[i]; }
    if (t == 1023) row_start[N] = part[1023];
}

__global__ void k_fill(const int* __restrict__ ei, int E, int N,
                       const int* __restrict__ row_start, int* __restrict__ cursor,
                       int* __restrict__ csr_src, int* __restrict__ csr_eid) {
    int e = blockIdx.x * blockDim.x + threadIdx.x;
    int Et = E + N;
    if (e >= Et) return;
    int d, s;
    if (e < E) { s = ei[e]; d = ei[E + e]; } else { s = e - E; d = s; }
    int pos = atomicAdd(&cursor[d], 1);
    int idx = row_start[d] + pos;
    csr_src[idx] = s;
    csr_eid[idx] = e;
}

// ---------------- conversions ----------------
__global__ void k_tofp16(const float* __restrict__ in, _Float16* __restrict__ out, int n4) {
    int i = blockIdx.x * blockDim.x + threadIdx.x;
    if (i >= n4) return;
    float4 v = reinterpret_cast<const float4*>(in)[i];
    half4v h;
    h[0] = (_Float16)v.x; h[1] = (_Float16)v.y;
    h[2] = (_Float16)v.z; h[3] = (_Float16)v.w;
    reinterpret_cast<half4v*>(out)[i] = h;
}

// W [K][Nc] fp32 -> Wt hi/lo [Nc][K] fp16
__global__ void k_tsplit(const float* __restrict__ W, _Float16* __restrict__ th,
                         _Float16* __restrict__ tl, int K, int Nc) {
    int idx = blockIdx.x * blockDim.x + threadIdx.x;
    if (idx >= K * Nc) return;
    int c = idx / K, k = idx - c * K;
    float v = W[(long)k * Nc + c];
    _Float16 hh = (_Float16)v;
    th[idx] = hh;
    tl[idx] = (_Float16)(v - (float)hh);
}

// ---------------- MFMA GEMM (fp16 2-pass) + fused attention-dot epilogue ----------------
// C = A[M,K](fp16) @ (Bh+Bl)[Nc,K]^T (fp16 split). Tile 128x128, BK=32, 4 waves.
// 1-D grid with XCD panel affinity: panel=(bid>>5)*8+(bid&7), col=(bid>>3)&3
// -> the 4 column-blocks of a panel share one XCD's L2 (A fetched once).
// hpre written NODE-MAJOR fp16 [Mpad][512]; emits e_src/e_dst per (row, head).
__global__ __launch_bounds__(256) void k_gemm_mfma(const _Float16* __restrict__ A,
                                                   const _Float16* __restrict__ Bh,
                                                   const _Float16* __restrict__ Bl,
                                                   _Float16* __restrict__ Cc, int M, int K, int Pb,
                                                   const float* __restrict__ a_src, const float* __restrict__ a_dst,
                                                   float* __restrict__ e_src, float* __restrict__ e_dst) {
    __shared__ _Float16 lA[4096], lBh[4096], lBl[4096];
    int bid = blockIdx.x;
    int panel = ((bid >> 5) << 3) + (bid & 7);
    int colb  = (bid >> 3) & 3;
    if (panel >= Pb) return;           // block-uniform early exit
    int tid = threadIdx.x;
    int w = tid >> 6, lane = tid & 63;
    int wr = w >> 1, wc = w & 1;
    int r0 = panel * 128, c0 = colb * 128;
    f32x4 acc[4][4] = {};
    int frag_off = ((lane >> 4) * 16 + (lane & 15)) * 8;

    for (int k0 = 0; k0 < K; k0 += 32) {
        __syncthreads();
        #pragma unroll
        for (int it = 0; it < 2; ++it) {
            int slot = it * 256 + tid;
            int rb = slot >> 6, kc = (slot >> 4) & 3, r16 = slot & 15;
            long ga = (long)(r0 + rb * 16 + r16) * K + k0 + kc * 8;
            long gb = (long)(c0 + rb * 16 + r16) * K + k0 + kc * 8;
            int ldst = (it * 256 + w * 64) * 8;
            GLOAD_LDS16(A + ga, lA + ldst);
            GLOAD_LDS16(Bh + gb, lBh + ldst);
            GLOAD_LDS16(Bl + gb, lBl + ldst);
        }
        __syncthreads();
        half8v fa[4], fbh[4], fbl[4];
        #pragma unroll
        for (int m = 0; m < 4; ++m) {
            int sa = (wr * 4 + m) * 512 + frag_off;
            fa[m] = *reinterpret_cast<half8v*>(&lA[sa]);
            int sb = (wc * 4 + m) * 512 + frag_off;
            fbh[m] = *reinterpret_cast<half8v*>(&lBh[sb]);
            fbl[m] = *reinterpret_cast<half8v*>(&lBl[sb]);
        }
        #pragma unroll
        for (int m = 0; m < 4; ++m)
            #pragma unroll
            for (int n = 0; n < 4; ++n) {
                acc[m][n] = __builtin_amdgcn_mfma_f32_16x16x32_f16(fa[m], fbh[n], acc[m][n], 0, 0, 0);
                acc[m][n] = __builtin_amdgcn_mfma_f32_16x16x32_f16(fa[m], fbl[n], acc[m][n], 0, 0, 0);
            }
    }
    int head = colb * 2 + wc;
    #pragma unroll
    for (int m = 0; m < 4; ++m)
        #pragma unroll
        for (int j = 0; j < 4; ++j) {
            int gr = r0 + wr * 64 + m * 16 + (lane >> 4) * 4 + j;
            if (gr < M) {
                #pragma unroll
                for (int n = 0; n < 4; ++n)
                    Cc[(long)gr * HC + head * 64 + n * 16 + (lane & 15)] = (_Float16)acc[m][n][j];
            }
        }
    // fused attention dots: this wave owns `head` for its 64 rows
    float asv[4], adv[4];
    #pragma unroll
    for (int nn = 0; nn < 4; ++nn) {
        asv[nn] = a_src[head * 64 + nn * 16 + (lane & 15)];
        adv[nn] = a_dst[head * 64 + nn * 16 + (lane & 15)];
    }
    #pragma unroll
    for (int m = 0; m < 4; ++m)
        #pragma unroll
        for (int j = 0; j < 4; ++j) {
            int gr = r0 + wr * 64 + m * 16 + (lane >> 4) * 4 + j;
            float es = 0.f, ed = 0.f;
            #pragma unroll
            for (int nn = 0; nn < 4; ++nn) {
                es = fmaf(acc[m][nn][j], asv[nn], es);
                ed = fmaf(acc[m][nn][j], adv[nn], ed);
            }
            #pragma unroll
            for (int o = 1; o < 16; o <<= 1) {
                es += __shfl_xor(es, o);
                ed += __shfl_xor(ed, o);
            }
            if ((lane & 15) == 0 && gr < M) {
                e_src[gr * 8 + head] = es;
                e_dst[gr * 8 + head] = ed;
            }
        }
}

// ---------------- per-node softmax + aggregation + alpha (all 8 heads) ----------------
// One wave per node. P-layout: lane = eg*8 + h. Gather layout: lane = h*8 + cg.
// No max-subtraction (e bounded, softmax shift-invariant).
// csr loads software-pipelined; src/eid cached in LDS for deg<=64.
__global__ __launch_bounds__(512) void k_agg(const half8v* __restrict__ hp8,
                                             const float* __restrict__ e_src,
                                             const float* __restrict__ e_dst,
                                             const int* __restrict__ row_start,
                                             const int* __restrict__ csr_src,
                                             const int* __restrict__ csr_eid,
                                             const float* __restrict__ bias,
                                             float* __restrict__ h2out,
                                             _Float16* __restrict__ h1,
                                             float* __restrict__ alpha,
                                             int N, int concat) {
    __shared__ float pbuf[8][512];
    __shared__ int   sibuf[8][64];
    __shared__ int   eibuf[8][64];
    int wid = threadIdx.x >> 6, lane = threadIdx.x & 63;
    int n = blockIdx.x * 8 + wid;
    if (n >= N) return;                // wave-uniform, no block barriers
    int lo3 = lane & 7, hi3 = lane >> 3;
    int row = row_start[n];
    int deg = row_start[n + 1] - row;
    int chunks = (deg + 7) >> 3;
    bool small = (deg <= 64);
    float* pw = &pbuf[wid][0];
    float ed = e_dst[n * 8 + lo3];
    // P1: psum over all edges (prefetched csr loads)
    float psum = 0.f;
    int idx0 = row + min(lo3, deg - 1);
    int sraw = csr_src[idx0];
    int eidr = csr_eid[idx0];
    for (int c = 0; c < chunks; ++c) {
        int sraw_c = sraw, eidr_c = eidr;
        if (c + 1 < chunks) {
            int idxn = row + min((c + 1) * 8 + lo3, deg - 1);
            sraw = csr_src[idxn];
            eidr = csr_eid[idxn];
        }
        if (small) { sibuf[wid][c * 8 + lo3] = sraw_c; eibuf[wid][c * 8 + lo3] = eidr_c; }
        int sv = __shfl(sraw_c, hi3);
        float es = e_src[sv * 8 + lo3];
        float p = __expf(leaky(es + ed));
        if (c * 8 + hi3 >= deg) p = 0.f;
        psum += p;
        if (small) pw[c * 64 + lane] = p;
    }
    psum += __shfl_xor(psum, 8);
    psum += __shfl_xor(psum, 16);
    psum += __shfl_xor(psum, 32);
    float inv = 1.0f / psum;
    // P2: alpha write + feature gather
    float acc[8] = {};
    for (int c = 0; c < chunks; ++c) {
        float p; int sraw_c, eidr_c;
        if (small) {
            sraw_c = sibuf[wid][c * 8 + lo3];
            eidr_c = eibuf[wid][c * 8 + lo3];
            p = pw[c * 64 + lane];
        } else {
            int idx = row + min(c * 8 + lo3, deg - 1);
            sraw_c = csr_src[idx];
            eidr_c = csr_eid[idx];
            int sv = __shfl(sraw_c, hi3);
            float es = e_src[sv * 8 + lo3];
            p = __expf(leaky(es + ed));
            if (c * 8 + hi3 >= deg) p = 0.f;
        }
        int eid = __shfl(eidr_c, hi3);
        if (c * 8 + hi3 < deg)
            alpha[(long)eid * 8 + lo3] = p * inv;
        #pragma unroll
        for (int eg = 0; eg < 8; ++eg) {
            float pe = __shfl(p, eg * 8 + hi3);
            int   se = __shfl(sraw_c, eg);
            half8v hv = hp8[(long)se * 64 + lane];
            #pragma unroll
            for (int k = 0; k < 8; ++k)
                acc[k] = fmaf((float)hv[k], pe, acc[k]);
        }
    }
    float invg = __shfl(inv, hi3);
    if (concat) {
        const float4* b4 = reinterpret_cast<const float4*>(bias);
        float4 ba = b4[lane * 2], bb = b4[lane * 2 + 1];
        float bv[8] = {ba.x, ba.y, ba.z, ba.w, bb.x, bb.y, bb.z, bb.w};
        half8v hh;
        #pragma unroll
        for (int k = 0; k < 8; ++k) {
            float v = fmaf(acc[k], invg, bv[k]);
            v = v > 0.f ? v : 0.f;
            hh[k] = (_Float16)v;
        }
        reinterpret_cast<half8v*>(h1)[(long)n * 64 + lane] = hh;
    } else {
        float sc = invg * 0.125f;
        #pragma unroll
        for (int k = 0; k < 8; ++k) acc[k] *= sc;
        #pragma unroll
        for (int o = 8; o <= 32; o <<= 1)
            #pragma unroll
            for (int k = 0; k < 8; ++k)
                acc[k] += __shfl_xor(acc[k], o);
        if (hi3 == 0) {
            float4 r0, r1;
            r0.x = acc[0] + bias[lo3 * 8 + 0];
            r0.y = acc[1] + bias[lo3 * 8 + 1];
            r0.z = acc[2] + bias[lo3 * 8 + 2];
            r0.w = acc[3] + bias[lo3 * 8 + 3];
            r1.x = acc[4] + bias[lo3 * 8 + 4];
            r1.y = acc[5] + bias[lo3 * 8 + 5];
            r1.z = acc[6] + bias[lo3 * 8 + 6];
            r1.w = acc[7] + bias[lo3 * 8 + 7];
            float4* o4 = reinterpret_cast<float4*>(h2out + (long)n * 64 + lo3 * 8);
            o4[0] = r0;
            o4[1] = r1;
        }
    }
}

extern "C" void kernel_launch(void* const* d_in, const int* in_sizes, int n_in,
                              void* d_out, int out_size, void* d_ws, size_t ws_size,
                              hipStream_t stream) {
    const float* x   = (const float*)d_in[0];
    const int*   ei  = (const int*)d_in[1];
    const float* W1  = (const float*)d_in[2];
    const float* as1 = (const float*)d_in[3];
    const float* ad1 = (const float*)d_in[4];
    const float* b1  = (const float*)d_in[5];
    const float* W2  = (const float*)d_in[6];
    const float* as2 = (const float*)d_in[7];
    const float* ad2 = (const float*)d_in[8];
    const float* b2  = (const float*)d_in[9];

    int N  = in_sizes[0] / 256;
    int E  = in_sizes[1] / 2;
    int Et = E + N;
    int K1 = 256;
    int Mb   = (N + 127) / 128;
    int Mpad = Mb * 128;

    float* out    = (float*)d_out;
    float* h2_out = out;
    float* alpha1 = out + (size_t)N * 64;
    float* alpha2 = alpha1 + (size_t)Et * H;

    _Float16* hpre = (_Float16*)d_ws;                      // [Mpad][512]
    _Float16* h1   = hpre + (size_t)Mpad * HC;             // [Mpad][512]
    _Float16* xh   = h1 + (size_t)Mpad * HC;               // [Mpad][256]
    _Float16* W1th = xh + (size_t)Mpad * K1;               // [512][256]
    _Float16* W1tl = W1th + (size_t)HC * K1;
    _Float16* W2th = W1tl + (size_t)HC * K1;               // [512][512]
    _Float16* W2tl = W2th + (size_t)HC * HC;
    float* eS     = (float*)(W2tl + (size_t)HC * HC);      // [N][8]
    float* eD     = eS + (size_t)N * H;
    int*   deg    = (int*)(eD + (size_t)N * H);
    int*   cursor = deg + N;
    int*   row_st = cursor + N;
    int*   csr_src= row_st + N + 1;                        // Et
    int*   csr_eid= csr_src + Et;                          // Et

    hipMemsetAsync(deg, 0, (size_t)2 * N * sizeof(int), stream);
    int tb = 256;
    k_degree<<<(Et + tb - 1) / tb, tb, 0, stream>>>(ei, E, N, deg);
    k_scan<<<1, 1024, 0, stream>>>(deg, N, row_st);
    k_fill<<<(Et + tb - 1) / tb, tb, 0, stream>>>(ei, E, N, row_st, cursor, csr_src, csr_eid);

    int n4 = N * K1 / 4;
    k_tofp16<<<(n4 + tb - 1) / tb, tb, 0, stream>>>(x, xh, n4);
    k_tsplit<<<(K1 * HC + tb - 1) / tb, tb, 0, stream>>>(W1, W1th, W1tl, K1, HC);
    k_tsplit<<<(HC * HC + tb - 1) / tb, tb, 0, stream>>>(W2, W2th, W2tl, HC, HC);

    int Pb8 = ((Mb + 7) / 8) * 8;
    int ggemm = Pb8 * 4;              // 1-D, XCD panel-affinity mapping in-kernel
    int gagg = (N + 7) / 8;
    // layer 1
    k_gemm_mfma<<<ggemm, 256, 0, stream>>>(xh, W1th, W1tl, hpre, N, K1, Mb, as1, ad1, eS, eD);
    k_agg<<<gagg, 512, 0, stream>>>((const half8v*)hpre, eS, eD, row_st, csr_src, csr_eid,
                                    b1, nullptr, h1, alpha1, N, 1);
    // layer 2
    k_gemm_mfma<<<ggemm, 256, 0, stream>>>(h1, W2th, W2tl, hpre, N, HC, Mb, as2, ad2, eS, eD);
    k_agg<<<gagg, 512, 0, stream>>>((const half8v*)hpre, eS, eD, row_st, csr_src, csr_eid,
                                    b2, h2_out, nullptr, alpha2, N, 0);
}

// Round 8
// 258.796 us; speedup vs baseline: 1.8735x; 1.0614x over previous
//
#include <hip/hip_runtime.h>

#define H 8
#define C 64
#define HC 512
#define NEG 0.2f

typedef __attribute__((ext_vector_type(8))) _Float16 half8v;
typedef __attribute__((ext_vector_type(4))) _Float16 half4v;
typedef __attribute__((ext_vector_type(4))) float f32x4;

__device__ __forceinline__ float leaky(float x) { return x > 0.f ? x : NEG * x; }

#define GLOAD_LDS16(gp, lp) \
  __builtin_amdgcn_global_load_lds((const __attribute__((address_space(1))) unsigned int*)(gp), \
                                   (__attribute__((address_space(3))) unsigned int*)(lp), 16, 0, 0)

// ---------------- CSR build (dst-sorted) ----------------
__global__ void k_degree(const int* __restrict__ ei, int E, int N, int* __restrict__ deg) {
    int e = blockIdx.x * blockDim.x + threadIdx.x;
    int Et = E + N;
    if (e >= Et) return;
    int d = (e < E) ? ei[E + e] : (e - E);
    atomicAdd(&deg[d], 1);
}

__global__ __launch_bounds__(1024) void k_scan(const int* __restrict__ deg, int N, int* __restrict__ row_start) {
    __shared__ int part[1024];
    int t = threadIdx.x;
    int chunk = (N + 1023) >> 10;
    int lo = t * chunk, hi = min(lo + chunk, N);
    int s = 0;
    for (int i = lo; i < hi; ++i) s += deg[i];
    part[t] = s;
    __syncthreads();
    for (int off = 1; off < 1024; off <<= 1) {
        int v = (t >= off) ? part[t - off] : 0;
        __syncthreads();
        part[t] += v;
        __syncthreads();
    }
    int base = (t == 0) ? 0 : part[t - 1];
    for (int i = lo; i < hi; ++i) { row_start[i] = base; base += deg[i]; }
    if (t == 1023) row_start[N] = part[1023];
}

__global__ void k_fill(const int* __restrict__ ei, int E, int N,
                       const int* __restrict__ row_start, int* __restrict__ cursor,
                       int* __restrict__ csr_src, int* __restrict__ csr_eid) {
    int e = blockIdx.x * blockDim.x + threadIdx.x;
    int Et = E + N;
    if (e >= Et) return;
    int d, s;
    if (e < E) { s = ei[e]; d = ei[E + e]; } else { s = e - E; d = s; }
    int pos = atomicAdd(&cursor[d], 1);
    int idx = row_start[d] + pos;
    csr_src[idx] = s;
    csr_eid[idx] = e;
}

// ---------------- conversions ----------------
__global__ void k_tofp16(const float* __restrict__ in, _Float16* __restrict__ out, int n4) {
    int i = blockIdx.x * blockDim.x + threadIdx.x;
    if (i >= n4) return;
    float4 v = reinterpret_cast<const float4*>(in)[i];
    half4v h;
    h[0] = (_Float16)v.x; h[1] = (_Float16)v.y;
    h[2] = (_Float16)v.z; h[3] = (_Float16)v.w;
    reinterpret_cast<half4v*>(out)[i] = h;
}

// W [K][Nc] fp32 -> Wt hi/lo [Nc][K] fp16
__global__ void k_tsplit(const float* __restrict__ W, _Float16* __restrict__ th,
                         _Float16* __restrict__ tl, int K, int Nc) {
    int idx = blockIdx.x * blockDim.x + threadIdx.x;
    if (idx >= K * Nc) return;
    int c = idx / K, k = idx - c * K;
    float v = W[(long)k * Nc + c];
    _Float16 hh = (_Float16)v;
    th[idx] = hh;
    tl[idx] = (_Float16)(v - (float)hh);
}

// ---------------- MFMA GEMM (fp16 2-pass) + fused attention-dot epilogue ----------------
// 2-phase double-buffered K-loop (T3-minimum): STAGE(t+1) issued BEFORE compute(t),
// one __syncthreads (vmcnt0+lgkmcnt0+barrier) per K-step hands off the buffers.
// Tile 128x128, BK=32, 4 waves; XCD panel-affinity 1-D grid.
__global__ __launch_bounds__(256) void k_gemm_mfma(const _Float16* __restrict__ A,
                                                   const _Float16* __restrict__ Bh,
                                                   const _Float16* __restrict__ Bl,
                                                   _Float16* __restrict__ Cc, int M, int K, int Pb,
                                                   const float* __restrict__ a_src, const float* __restrict__ a_dst,
                                                   float* __restrict__ e_src, float* __restrict__ e_dst) {
    __shared__ _Float16 lA[8192], lBh[8192], lBl[8192];   // 2 buffers x 4096
    int bid = blockIdx.x;
    int panel = ((bid >> 5) << 3) + (bid & 7);
    int colb  = (bid >> 3) & 3;
    if (panel >= Pb) return;           // block-uniform early exit (before any barrier)
    int tid = threadIdx.x;
    int w = tid >> 6, lane = tid & 63;
    int wr = w >> 1, wc = w & 1;
    int r0 = panel * 128, c0 = colb * 128;
    f32x4 acc[4][4] = {};
    int frag_off = ((lane >> 4) * 16 + (lane & 15)) * 8;

    // per-thread staging geometry (constant across iters)
    int rb0 = tid >> 6, kc0 = (tid >> 4) & 3, r16_0 = tid & 15;        // it=0 slot
    int rb1 = (256 + tid) >> 6, kc1 = ((256 + tid) >> 4) & 3;          // it=1 slot
    long gaBase0 = (long)(r0 + rb0 * 16 + r16_0) * K + kc0 * 8;
    long gbBase0 = (long)(c0 + rb0 * 16 + r16_0) * K + kc0 * 8;
    long gaBase1 = (long)(r0 + rb1 * 16 + r16_0) * K + kc1 * 8;
    long gbBase1 = (long)(c0 + rb1 * 16 + r16_0) * K + kc1 * 8;
    int ldst0 = (w * 64) * 8;
    int ldst1 = (256 + w * 64) * 8;

#define STAGE(buf, k0)  do { \
        int off = (buf) * 4096; \
        GLOAD_LDS16(A  + gaBase0 + (k0), lA  + off + ldst0); \
        GLOAD_LDS16(Bh + gbBase0 + (k0), lBh + off + ldst0); \
        GLOAD_LDS16(Bl + gbBase0 + (k0), lBl + off + ldst0); \
        GLOAD_LDS16(A  + gaBase1 + (k0), lA  + off + ldst1); \
        GLOAD_LDS16(Bh + gbBase1 + (k0), lBh + off + ldst1); \
        GLOAD_LDS16(Bl + gbBase1 + (k0), lBl + off + ldst1); \
    } while (0)

    int nk = K >> 5;
    STAGE(0, 0);
    __syncthreads();                   // vmcnt(0) drain + barrier: buf0 ready
    int cur = 0;
    for (int t = 0; t < nk; ++t) {
        if (t + 1 < nk) STAGE(cur ^ 1, (t + 1) * 32);   // prefetch overlaps compute below
        int off = cur * 4096;
        half8v fa[4], fbh[4], fbl[4];
        #pragma unroll
        for (int m = 0; m < 4; ++m) {
            int sa = off + (wr * 4 + m) * 512 + frag_off;
            fa[m] = *reinterpret_cast<half8v*>(&lA[sa]);
            int sb = off + (wc * 4 + m) * 512 + frag_off;
            fbh[m] = *reinterpret_cast<half8v*>(&lBh[sb]);
            fbl[m] = *reinterpret_cast<half8v*>(&lBl[sb]);
        }
        #pragma unroll
        for (int m = 0; m < 4; ++m)
            #pragma unroll
            for (int n = 0; n < 4; ++n) {
                acc[m][n] = __builtin_amdgcn_mfma_f32_16x16x32_f16(fa[m], fbh[n], acc[m][n], 0, 0, 0);
                acc[m][n] = __builtin_amdgcn_mfma_f32_16x16x32_f16(fa[m], fbl[n], acc[m][n], 0, 0, 0);
            }
        __syncthreads();               // drains this wave's STAGE(t+1) + orders reads-before-overwrite
        cur ^= 1;
    }
#undef STAGE

    int head = colb * 2 + wc;
    #pragma unroll
    for (int m = 0; m < 4; ++m)
        #pragma unroll
        for (int j = 0; j < 4; ++j) {
            int gr = r0 + wr * 64 + m * 16 + (lane >> 4) * 4 + j;
            if (gr < M) {
                #pragma unroll
                for (int n = 0; n < 4; ++n)
                    Cc[(long)gr * HC + head * 64 + n * 16 + (lane & 15)] = (_Float16)acc[m][n][j];
            }
        }
    // fused attention dots: this wave owns `head` for its 64 rows
    float asv[4], adv[4];
    #pragma unroll
    for (int nn = 0; nn < 4; ++nn) {
        asv[nn] = a_src[head * 64 + nn * 16 + (lane & 15)];
        adv[nn] = a_dst[head * 64 + nn * 16 + (lane & 15)];
    }
    #pragma unroll
    for (int m = 0; m < 4; ++m)
        #pragma unroll
        for (int j = 0; j < 4; ++j) {
            int gr = r0 + wr * 64 + m * 16 + (lane >> 4) * 4 + j;
            float es = 0.f, ed = 0.f;
            #pragma unroll
            for (int nn = 0; nn < 4; ++nn) {
                es = fmaf(acc[m][nn][j], asv[nn], es);
                ed = fmaf(acc[m][nn][j], adv[nn], ed);
            }
            #pragma unroll
            for (int o = 1; o < 16; o <<= 1) {
                es += __shfl_xor(es, o);
                ed += __shfl_xor(ed, o);
            }
            if ((lane & 15) == 0 && gr < M) {
                e_src[gr * 8 + head] = es;
                e_dst[gr * 8 + head] = ed;
            }
        }
}

// ---------------- per-node softmax + aggregation + alpha (all 8 heads) ----------------
__global__ __launch_bounds__(512) void k_agg(const half8v* __restrict__ hp8,
                                             const float* __restrict__ e_src,
                                             const float* __restrict__ e_dst,
                                             const int* __restrict__ row_start,
                                             const int* __restrict__ csr_src,
                                             const int* __restrict__ csr_eid,
                                             const float* __restrict__ bias,
                                             float* __restrict__ h2out,
                                             _Float16* __restrict__ h1,
                                             float* __restrict__ alpha,
                                             int N, int concat) {
    __shared__ float pbuf[8][512];
    __shared__ int   sibuf[8][64];
    __shared__ int   eibuf[8][64];
    int wid = threadIdx.x >> 6, lane = threadIdx.x & 63;
    int n = blockIdx.x * 8 + wid;
    if (n >= N) return;                // wave-uniform, no block barriers
    int lo3 = lane & 7, hi3 = lane >> 3;
    int row = row_start[n];
    int deg = row_start[n + 1] - row;
    int chunks = (deg + 7) >> 3;
    bool small = (deg <= 64);
    float* pw = &pbuf[wid][0];
    float ed = e_dst[n * 8 + lo3];
    float psum = 0.f;
    int idx0 = row + min(lo3, deg - 1);
    int sraw = csr_src[idx0];
    int eidr = csr_eid[idx0];
    for (int c = 0; c < chunks; ++c) {
        int sraw_c = sraw, eidr_c = eidr;
        if (c + 1 < chunks) {
            int idxn = row + min((c + 1) * 8 + lo3, deg - 1);
            sraw = csr_src[idxn];
            eidr = csr_eid[idxn];
        }
        if (small) { sibuf[wid][c * 8 + lo3] = sraw_c; eibuf[wid][c * 8 + lo3] = eidr_c; }
        int sv = __shfl(sraw_c, hi3);
        float es = e_src[sv * 8 + lo3];
        float p = __expf(leaky(es + ed));
        if (c * 8 + hi3 >= deg) p = 0.f;
        psum += p;
        if (small) pw[c * 64 + lane] = p;
    }
    psum += __shfl_xor(psum, 8);
    psum += __shfl_xor(psum, 16);
    psum += __shfl_xor(psum, 32);
    float inv = 1.0f / psum;
    float acc[8] = {};
    for (int c = 0; c < chunks; ++c) {
        float p; int sraw_c, eidr_c;
        if (small) {
            sraw_c = sibuf[wid][c * 8 + lo3];
            eidr_c = eibuf[wid][c * 8 + lo3];
            p = pw[c * 64 + lane];
        } else {
            int idx = row + min(c * 8 + lo3, deg - 1);
            sraw_c = csr_src[idx];
            eidr_c = csr_eid[idx];
            int sv = __shfl(sraw_c, hi3);
            float es = e_src[sv * 8 + lo3];
            p = __expf(leaky(es + ed));
            if (c * 8 + hi3 >= deg) p = 0.f;
        }
        int eid = __shfl(eidr_c, hi3);
        if (c * 8 + hi3 < deg)
            alpha[(long)eid * 8 + lo3] = p * inv;
        #pragma unroll
        for (int eg = 0; eg < 8; ++eg) {
            float pe = __shfl(p, eg * 8 + hi3);
            int   se = __shfl(sraw_c, eg);
            half8v hv = hp8[(long)se * 64 + lane];
            #pragma unroll
            for (int k = 0; k < 8; ++k)
                acc[k] = fmaf((float)hv[k], pe, acc[k]);
        }
    }
    float invg = __shfl(inv, hi3);
    if (concat) {
        const float4* b4 = reinterpret_cast<const float4*>(bias);
        float4 ba = b4[lane * 2], bb = b4[lane * 2 + 1];
        float bv[8] = {ba.x, ba.y, ba.z, ba.w, bb.x, bb.y, bb.z, bb.w};
        half8v hh;
        #pragma unroll
        for (int k = 0; k < 8; ++k) {
            float v = fmaf(acc[k], invg, bv[k]);
            v = v > 0.f ? v : 0.f;
            hh[k] = (_Float16)v;
        }
        reinterpret_cast<half8v*>(h1)[(long)n * 64 + lane] = hh;
    } else {
        float sc = invg * 0.125f;
        #pragma unroll
        for (int k = 0; k < 8; ++k) acc[k] *= sc;
        #pragma unroll
        for (int o = 8; o <= 32; o <<= 1)
            #pragma unroll
            for (int k = 0; k < 8; ++k)
                acc[k] += __shfl_xor(acc[k], o);
        if (hi3 == 0) {
            float4 r0, r1;
            r0.x = acc[0] + bias[lo3 * 8 + 0];
            r0.y = acc[1] + bias[lo3 * 8 + 1];
            r0.z = acc[2] + bias[lo3 * 8 + 2];
            r0.w = acc[3] + bias[lo3 * 8 + 3];
            r1.x = acc[4] + bias[lo3 * 8 + 4];
            r1.y = acc[5] + bias[lo3 * 8 + 5];
            r1.z = acc[6] + bias[lo3 * 8 + 6];
            r1.w = acc[7] + bias[lo3 * 8 + 7];
            float4* o4 = reinterpret_cast<float4*>(h2out + (long)n * 64 + lo3 * 8);
            o4[0] = r0;
            o4[1] = r1;
        }
    }
}

extern "C" void kernel_launch(void* const* d_in, const int* in_sizes, int n_in,
                              void* d_out, int out_size, void* d_ws, size_t ws_size,
                              hipStream_t stream) {
    const float* x   = (const float*)d_in[0];
    const int*   ei  = (const int*)d_in[1];
    const float* W1  = (const float*)d_in[2];
    const float* as1 = (const float*)d_in[3];
    const float* ad1 = (const float*)d_in[4];
    const float* b1  = (const float*)d_in[5];
    const float* W2  = (const float*)d_in[6];
    const float* as2 = (const float*)d_in[7];
    const float* ad2 = (const float*)d_in[8];
    const float* b2  = (const float*)d_in[9];

    int N  = in_sizes[0] / 256;
    int E  = in_sizes[1] / 2;
    int Et = E + N;
    int K1 = 256;
    int Mb   = (N + 127) / 128;
    int Mpad = Mb * 128;

    float* out    = (float*)d_out;
    float* h2_out = out;
    float* alpha1 = out + (size_t)N * 64;
    float* alpha2 = alpha1 + (size_t)Et * H;

    _Float16* hpre = (_Float16*)d_ws;                      // [Mpad][512]
    _Float16* h1   = hpre + (size_t)Mpad * HC;             // [Mpad][512]
    _Float16* xh   = h1 + (size_t)Mpad * HC;               // [Mpad][256]
    _Float16* W1th = xh + (size_t)Mpad * K1;               // [512][256]
    _Float16* W1tl = W1th + (size_t)HC * K1;
    _Float16* W2th = W1tl + (size_t)HC * K1;               // [512][512]
    _Float16* W2tl = W2th + (size_t)HC * HC;
    float* eS     = (float*)(W2tl + (size_t)HC * HC);      // [N][8]
    float* eD     = eS + (size_t)N * H;
    int*   deg    = (int*)(eD + (size_t)N * H);
    int*   cursor = deg + N;
    int*   row_st = cursor + N;
    int*   csr_src= row_st + N + 1;                        // Et
    int*   csr_eid= csr_src + Et;                          // Et

    hipMemsetAsync(deg, 0, (size_t)2 * N * sizeof(int), stream);
    int tb = 256;
    k_degree<<<(Et + tb - 1) / tb, tb, 0, stream>>>(ei, E, N, deg);
    k_scan<<<1, 1024, 0, stream>>>(deg, N, row_st);
    k_fill<<<(Et + tb - 1) / tb, tb, 0, stream>>>(ei, E, N, row_st, cursor, csr_src, csr_eid);

    int n4 = N * K1 / 4;
    k_tofp16<<<(n4 + tb - 1) / tb, tb, 0, stream>>>(x, xh, n4);
    k_tsplit<<<(K1 * HC + tb - 1) / tb, tb, 0, stream>>>(W1, W1th, W1tl, K1, HC);
    k_tsplit<<<(HC * HC + tb - 1) / tb, tb, 0, stream>>>(W2, W2th, W2tl, HC, HC);

    int Pb8 = ((Mb + 7) / 8) * 8;
    int ggemm = Pb8 * 4;              // 1-D, XCD panel-affinity mapping in-kernel
    int gagg = (N + 7) / 8;
    // layer 1
    k_gemm_mfma<<<ggemm, 256, 0, stream>>>(xh, W1th, W1tl, hpre, N, K1, Mb, as1, ad1, eS, eD);
    k_agg<<<gagg, 512, 0, stream>>>((const half8v*)hpre, eS, eD, row_st, csr_src, csr_eid,
                                    b1, nullptr, h1, alpha1, N, 1);
    // layer 2
    k_gemm_mfma<<<ggemm, 256, 0, stream>>>(h1, W2th, W2tl, hpre, N, HC, Mb, as2, ad2, eS, eD);
    k_agg<<<gagg, 512, 0, stream>>>((const half8v*)hpre, eS, eD, row_st, csr_src, csr_eid,
                                    b2, h2_out, nullptr, alpha2, N, 0);
}